// Round 6
// baseline (108.244 us; speedup 1.0000x reference)
//
#include <hip/hip_runtime.h>
#include <hip/hip_bf16.h>

typedef __bf16 bf16x8 __attribute__((ext_vector_type(8)));
typedef float  f32x4  __attribute__((ext_vector_type(4)));

#define NN 4096
#define DK 128
#define BM 128
#define BN 128
#define NMAX 0.99f

__global__ __launch_bounds__(512, 4)
void hyp_dist_kernel(const float* __restrict__ X, const float* __restrict__ Y,
                     float* __restrict__ Out)
{
    // Manual LDS layout so the 64 KB a/b tile region can be reused as the
    // f32 output-staging tile after the MFMA phase (tiles are dead then).
    __shared__ alignas(16) char smem[BM * DK * 2 + BN * DK * 2 + (BM + BN) * 4];
    __bf16* aL  = (__bf16*)smem;                       // 32 KB
    __bf16* bL  = (__bf16*)(smem + BM * DK * 2);       // 32 KB
    float*  oT  = (float*)smem;                        // aliases aL+bL (64 KB)
    float*  xsL = (float*)(smem + BM * DK * 2 + BN * DK * 2);   // 512 B
    float*  ysL = xsL + BM;                                     // 512 B

    const int tid  = threadIdx.x;
    const int bz   = blockIdx.z;
    const int brow = blockIdx.y * BM;
    const int bcol = blockIdx.x * BN;

    const float* xb = X + ((size_t)bz * NN + brow) * DK;
    const float* yb = Y + ((size_t)bz * NN + bcol) * DK;

    const int c16 = tid & 15;   // 16B (8-elem) chunk within a row
    const int rr  = tid >> 4;   // 32 rows per pass (512 threads)

    // ---- Stage x/y tiles: f32 -> bf16 LDS (swizzled) + row sums of squares.
#pragma unroll
    for (int p = 0; p < 4; ++p) {
        const int r = p * 32 + rr;
        const f32x4* s4 = (const f32x4*)(xb + r * DK + c16 * 8);
        f32x4 v0 = s4[0], v1 = s4[1];
        float s = v0[0]*v0[0] + v0[1]*v0[1] + v0[2]*v0[2] + v0[3]*v0[3]
                + v1[0]*v1[0] + v1[1]*v1[1] + v1[2]*v1[2] + v1[3]*v1[3];
        s += __shfl_xor(s, 1);
        s += __shfl_xor(s, 2);
        s += __shfl_xor(s, 4);
        s += __shfl_xor(s, 8);
        if (c16 == 0) xsL[r] = s;
        bf16x8 pk;
        pk[0]=(__bf16)v0[0]; pk[1]=(__bf16)v0[1]; pk[2]=(__bf16)v0[2]; pk[3]=(__bf16)v0[3];
        pk[4]=(__bf16)v1[0]; pk[5]=(__bf16)v1[1]; pk[6]=(__bf16)v1[2]; pk[7]=(__bf16)v1[3];
        const int byt = (r * 256 + c16 * 16) ^ ((r & 7) << 4);
        *(bf16x8*)((char*)aL + byt) = pk;
    }
#pragma unroll
    for (int p = 0; p < 4; ++p) {
        const int r = p * 32 + rr;
        const f32x4* s4 = (const f32x4*)(yb + r * DK + c16 * 8);
        f32x4 v0 = s4[0], v1 = s4[1];
        float s = v0[0]*v0[0] + v0[1]*v0[1] + v0[2]*v0[2] + v0[3]*v0[3]
                + v1[0]*v1[0] + v1[1]*v1[1] + v1[2]*v1[2] + v1[3]*v1[3];
        s += __shfl_xor(s, 1);
        s += __shfl_xor(s, 2);
        s += __shfl_xor(s, 4);
        s += __shfl_xor(s, 8);
        if (c16 == 0) ysL[r] = s;
        bf16x8 pk;
        pk[0]=(__bf16)v0[0]; pk[1]=(__bf16)v0[1]; pk[2]=(__bf16)v0[2]; pk[3]=(__bf16)v0[3];
        pk[4]=(__bf16)v1[0]; pk[5]=(__bf16)v1[1]; pk[6]=(__bf16)v1[2]; pk[7]=(__bf16)v1[3];
        const int byt = (r * 256 + c16 * 16) ^ ((r & 7) << 4);
        *(bf16x8*)((char*)bL + byt) = pk;
    }
    __syncthreads();

    const int lane = tid & 63;
    const int wid  = tid >> 6;   // 8 waves: 2 (rows) x 4 (cols)
    const int wm   = wid >> 2;   // 64 output rows per wave
    const int wn   = wid & 3;    // 32 output cols per wave
    const int r16  = lane & 15;
    const int kg   = lane >> 4;

    f32x4 acc[4][2] = {};

#pragma unroll
    for (int ks = 0; ks < 4; ++ks) {
        const int kb = ks * 32 + kg * 8;
        bf16x8 af[4], bg[2];
#pragma unroll
        for (int i = 0; i < 4; ++i) {
            const int r = wm * 64 + i * 16 + r16;
            const int byt = (r * 256 + kb * 2) ^ ((r & 7) << 4);
            af[i] = *(const bf16x8*)((const char*)aL + byt);
        }
#pragma unroll
        for (int j = 0; j < 2; ++j) {
            const int r = wn * 32 + j * 16 + r16;
            const int byt = (r * 256 + kb * 2) ^ ((r & 7) << 4);
            bg[j] = *(const bf16x8*)((const char*)bL + byt);
        }
        // A=y-frag, B=x-frag: lane's 4 acc regs = 4 consecutive output cols.
#pragma unroll
        for (int i = 0; i < 4; ++i)
#pragma unroll
            for (int j = 0; j < 2; ++j)
                acc[i][j] = __builtin_amdgcn_mfma_f32_16x16x32_bf16(bg[j], af[i], acc[i][j], 0, 0, 0);
    }

    __syncthreads();   // all frag reads of aL/bL done before oT overwrites them

    // ---- Epilogue: compute into LDS out-tile (swizzled f32x4 writes).
    // num_sq = den*s, s = xs+ys-2dot; dn = s*rsqrt(s*den); out = ln((1+dn)/(1-dn)).
#pragma unroll
    for (int i = 0; i < 4; ++i) {
        const int r = wm * 64 + i * 16 + r16;
        const float u = xsL[r];
#pragma unroll
        for (int j = 0; j < 2; ++j) {
            const int cb = wn * 32 + j * 16 + kg * 4;
            const f32x4 v4 = *(const f32x4*)&ysL[cb];
            f32x4 o4;
#pragma unroll
            for (int q = 0; q < 4; ++q) {
                const float d  = acc[i][j][q];
                const float v  = v4[q];
                const float e1 = fmaf(-2.0f, d, 1.0f);
                const float den = fmaf(u, v, e1);
                float s = fmaf(-2.0f, d, u + v);
                s = fmaxf(s, 1e-12f);
                const float dn0 = s * __builtin_amdgcn_rsqf(s * den);
                const float dn = fminf(dn0, NMAX);
                o4[q] = __logf((1.0f + dn) * __builtin_amdgcn_rcpf(1.0f - dn));
            }
            const int byt = (r * (BN * 4) + cb * 4) ^ ((r & 7) << 4);
            *(f32x4*)((char*)oT + byt) = o4;
        }
    }

    __syncthreads();

    // ---- Linear cooperative store sweep: each instruction writes two full
    // 512 B row-chunks, walking the tile in address order.
    float* ob = Out + ((size_t)bz * NN + brow) * NN + bcol;
#pragma unroll
    for (int it = 0; it < 8; ++it) {
        const int w    = it * 2048 + tid * 4;   // word index in 128x128 tile
        const int row  = w >> 7;
        const int colw = w & 127;
        const int byt  = (row * (BN * 4) + colw * 4) ^ ((row & 7) << 4);
        const f32x4 o4 = *(const f32x4*)((const char*)oT + byt);
        *(f32x4*)(ob + (size_t)row * NN + colw) = o4;
    }
}

extern "C" void kernel_launch(void* const* d_in, const int* in_sizes, int n_in,
                              void* d_out, int out_size, void* d_ws, size_t ws_size,
                              hipStream_t stream) {
    const float* X = (const float*)d_in[0];
    const float* Y = (const float*)d_in[1];
    float* O = (float*)d_out;
    const int b = in_sizes[0] / (NN * DK);   // = 4
    dim3 grid(NN / BN, NN / BM, b);
    hyp_dist_kernel<<<grid, dim3(512), 0, stream>>>(X, Y, O);
}

// Round 7
// 72.372 us; speedup vs baseline: 1.4957x; 1.4957x over previous
//
#include <hip/hip_runtime.h>
#include <hip/hip_bf16.h>

typedef __bf16 bf16x8 __attribute__((ext_vector_type(8)));
typedef float  f32x4  __attribute__((ext_vector_type(4)));

#define NN 4096
#define DK 128
#define BM 128
#define BN 128
#define NMAX 0.99f
#define LN2F 0.69314718056f

// ws layout (bytes):
//   Xb  [b*32 tiles][16384 bf16]  @ 0          (4,194,304)
//   Yb  same                      @ 4,194,304  (4,194,304)
//   XC  [b*4096] float2 (xs, ln(1-xs)) @ 8,388,608 (131,072)
//   YC  same                      @ 8,519,680  (131,072)
#define WS_XB   0
#define WS_YB   (4u*4096u*DK*2u)
#define WS_XC   (2u*WS_YB)
#define WS_YC   (WS_XC + 4u*4096u*8u)
#define WS_REQ  (WS_YC + 4u*4096u*8u)

__device__ __forceinline__ void load_lds16(const void* g, void* l) {
    __builtin_amdgcn_global_load_lds(
        (const __attribute__((address_space(1))) unsigned int*)g,
        (__attribute__((address_space(3))) unsigned int*)l, 16, 0, 0);
}

// ---------------- pre-pass: f32 -> swizzled bf16 tile image + (xs, ln(1-xs)) ----
__global__ __launch_bounds__(256)
void prep_kernel(const float* __restrict__ X, const float* __restrict__ Y,
                 __bf16* __restrict__ Xb, __bf16* __restrict__ Yb,
                 float2* __restrict__ XC, float2* __restrict__ YC)
{
    const int tid = threadIdx.x;
    const int c16 = tid & 15;
    const int rl  = tid >> 4;                 // 16 rows per block
    const int gr  = blockIdx.x * 16 + rl;     // row within tensor (0..16383)

    const float* src = blockIdx.y ? Y : X;
    __bf16*      dst = blockIdx.y ? Yb : Xb;
    float2*      nc  = blockIdx.y ? YC : XC;

    const f32x4* s4 = (const f32x4*)(src + (size_t)gr * DK + c16 * 8);
    f32x4 v0 = s4[0], v1 = s4[1];
    float s = v0[0]*v0[0] + v0[1]*v0[1] + v0[2]*v0[2] + v0[3]*v0[3]
            + v1[0]*v1[0] + v1[1]*v1[1] + v1[2]*v1[2] + v1[3]*v1[3];
    s += __shfl_xor(s, 1);
    s += __shfl_xor(s, 2);
    s += __shfl_xor(s, 4);
    s += __shfl_xor(s, 8);

    bf16x8 pk;
    pk[0]=(__bf16)v0[0]; pk[1]=(__bf16)v0[1]; pk[2]=(__bf16)v0[2]; pk[3]=(__bf16)v0[3];
    pk[4]=(__bf16)v1[0]; pk[5]=(__bf16)v1[1]; pk[6]=(__bf16)v1[2]; pk[7]=(__bf16)v1[3];

    const int tile = gr >> 7;
    const int rloc = gr & 127;
    const int byt  = (rloc * 256 + c16 * 16) ^ ((rloc & 7) << 4);
    *(bf16x8*)((char*)(dst + (size_t)tile * (BM * DK)) + byt) = pk;

    if (c16 == 0) nc[gr] = make_float2(s, __logf(1.0f - s));
}

// ---------------- main kernel: async-staged bf16 tiles + MFMA + 2-trans epilogue --
__global__ __launch_bounds__(512, 4)
void hyp_main(const __bf16* __restrict__ Xb, const __bf16* __restrict__ Yb,
              const float2* __restrict__ XC, const float2* __restrict__ YC,
              float* __restrict__ Out)
{
    __shared__ alignas(16) __bf16 aL[BM * DK];   // 32 KB, swizzled image (linear DMA)
    __shared__ alignas(16) __bf16 bL[BN * DK];   // 32 KB
    __shared__ float2 xcL[BM];                   // (xs, ln(1-xs))
    __shared__ float2 ycL[BN];

    const int tid  = threadIdx.x;
    const int lane = tid & 63;
    const int wid  = tid >> 6;
    const int bz   = blockIdx.z;
    const int brow = blockIdx.y * BM;
    const int bcol = blockIdx.x * BN;

    const char* xt = (const char*)(Xb + (size_t)(bz * 32 + blockIdx.y) * (BM * DK));
    const char* yt = (const char*)(Yb + (size_t)(bz * 32 + blockIdx.x) * (BN * DK));

    // Each wave DMAs 4 KB of aL and 4 KB of bL (4 x 1KB each).
    {
        const int woff = wid * 4096;
#pragma unroll
        for (int j = 0; j < 4; ++j) {
            load_lds16(xt + woff + j * 1024 + lane * 16, (char*)aL + woff + j * 1024);
            load_lds16(yt + woff + j * 1024 + lane * 16, (char*)bL + woff + j * 1024);
        }
    }
    if (tid < 128)       xcL[tid]       = XC[bz * NN + brow + tid];
    else if (tid < 256)  ycL[tid - 128] = YC[bz * NN + bcol + (tid - 128)];
    __syncthreads();

    const int wm  = wid >> 2;   // 2x4 wave grid: 64 rows x 32 cols each
    const int wn  = wid & 3;
    const int r16 = lane & 15;
    const int kg  = lane >> 4;

    f32x4 acc[4][2] = {};

#pragma unroll
    for (int ks = 0; ks < 4; ++ks) {
        const int kb = ks * 32 + kg * 8;
        bf16x8 af[4], bg[2];
#pragma unroll
        for (int i = 0; i < 4; ++i) {
            const int r = wm * 64 + i * 16 + r16;
            const int byt = (r * 256 + kb * 2) ^ ((r & 7) << 4);
            af[i] = *(const bf16x8*)((const char*)aL + byt);
        }
#pragma unroll
        for (int j = 0; j < 2; ++j) {
            const int r = wn * 32 + j * 16 + r16;
            const int byt = (r * 256 + kb * 2) ^ ((r & 7) << 4);
            bg[j] = *(const bf16x8*)((const char*)bL + byt);
        }
        // A=y-frag, B=x-frag: lane's 4 acc regs = 4 consecutive output cols.
#pragma unroll
        for (int i = 0; i < 4; ++i)
#pragma unroll
            for (int j = 0; j < 2; ++j)
                acc[i][j] = __builtin_amdgcn_mfma_f32_16x16x32_bf16(bg[j], af[i], acc[i][j], 0, 0, 0);
    }

    // Epilogue: s = u+v-2d, den = 1-2d+uv, den-s = (1-u)(1-v) exactly, so
    // out = ln(den + s + 2*sqrt(s*den)) - ln(1-u) - ln(1-v).
    float* ob = Out + ((size_t)bz * NN + brow) * NN + bcol;
#pragma unroll
    for (int i = 0; i < 4; ++i) {
        const int r = wm * 64 + i * 16 + r16;
        const float2 xc = xcL[r];
        const float u = xc.x, cx = xc.y;
        float* orow = ob + (size_t)r * NN;
#pragma unroll
        for (int j = 0; j < 2; ++j) {
            const int cb = wn * 32 + j * 16 + kg * 4;
            const f32x4 y01 = *(const f32x4*)&ycL[cb];       // v0,c0,v1,c1
            const f32x4 y23 = *(const f32x4*)&ycL[cb + 2];   // v2,c2,v3,c3
            f32x4 o4;
#pragma unroll
            for (int q = 0; q < 4; ++q) {
                const float d  = acc[i][j][q];
                const float v  = (q < 2) ? y01[2 * q] : y23[2 * (q - 2)];
                const float cy = (q < 2) ? y01[2 * q + 1] : y23[2 * (q - 2) + 1];
                const float e1  = fmaf(-2.0f, d, 1.0f);
                const float den = fmaf(u, v, e1);
                float s = fmaf(-2.0f, d, u + v);
                s = fmaxf(s, 1e-12f);
                const float rt  = __builtin_amdgcn_sqrtf(s * den);
                const float arg = fmaf(2.0f, rt, den + s);
                o4[q] = fmaf(__log2f(arg), LN2F, -(cx + cy));
            }
            *(f32x4*)(orow + cb) = o4;
        }
    }
}

// ---------------- fallback (R3 structure) if ws is too small ----------------
__global__ __launch_bounds__(512, 4)
void hyp_fallback(const float* __restrict__ X, const float* __restrict__ Y,
                  float* __restrict__ Out)
{
    __shared__ alignas(16) __bf16 aL[BM * DK];
    __shared__ alignas(16) __bf16 bL[BN * DK];
    __shared__ float xsL[BM];
    __shared__ float ysL[BN];

    const int tid  = threadIdx.x;
    const int bz   = blockIdx.z;
    const int brow = blockIdx.y * BM;
    const int bcol = blockIdx.x * BN;
    const float* xb = X + ((size_t)bz * NN + brow) * DK;
    const float* yb = Y + ((size_t)bz * NN + bcol) * DK;
    const int c16 = tid & 15;
    const int rr  = tid >> 4;

#pragma unroll
    for (int p = 0; p < 4; ++p) {
        const int r = p * 32 + rr;
        const f32x4* s4 = (const f32x4*)(xb + r * DK + c16 * 8);
        f32x4 v0 = s4[0], v1 = s4[1];
        float s = v0[0]*v0[0] + v0[1]*v0[1] + v0[2]*v0[2] + v0[3]*v0[3]
                + v1[0]*v1[0] + v1[1]*v1[1] + v1[2]*v1[2] + v1[3]*v1[3];
        s += __shfl_xor(s, 1); s += __shfl_xor(s, 2);
        s += __shfl_xor(s, 4); s += __shfl_xor(s, 8);
        if (c16 == 0) xsL[r] = s;
        bf16x8 pk;
        pk[0]=(__bf16)v0[0]; pk[1]=(__bf16)v0[1]; pk[2]=(__bf16)v0[2]; pk[3]=(__bf16)v0[3];
        pk[4]=(__bf16)v1[0]; pk[5]=(__bf16)v1[1]; pk[6]=(__bf16)v1[2]; pk[7]=(__bf16)v1[3];
        const int byt = (r * 256 + c16 * 16) ^ ((r & 7) << 4);
        *(bf16x8*)((char*)aL + byt) = pk;
    }
#pragma unroll
    for (int p = 0; p < 4; ++p) {
        const int r = p * 32 + rr;
        const f32x4* s4 = (const f32x4*)(yb + r * DK + c16 * 8);
        f32x4 v0 = s4[0], v1 = s4[1];
        float s = v0[0]*v0[0] + v0[1]*v0[1] + v0[2]*v0[2] + v0[3]*v0[3]
                + v1[0]*v1[0] + v1[1]*v1[1] + v1[2]*v1[2] + v1[3]*v1[3];
        s += __shfl_xor(s, 1); s += __shfl_xor(s, 2);
        s += __shfl_xor(s, 4); s += __shfl_xor(s, 8);
        if (c16 == 0) ysL[r] = s;
        bf16x8 pk;
        pk[0]=(__bf16)v0[0]; pk[1]=(__bf16)v0[1]; pk[2]=(__bf16)v0[2]; pk[3]=(__bf16)v0[3];
        pk[4]=(__bf16)v1[0]; pk[5]=(__bf16)v1[1]; pk[6]=(__bf16)v1[2]; pk[7]=(__bf16)v1[3];
        const int byt = (r * 256 + c16 * 16) ^ ((r & 7) << 4);
        *(bf16x8*)((char*)bL + byt) = pk;
    }
    __syncthreads();

    const int lane = tid & 63;
    const int wid  = tid >> 6;
    const int wm   = wid >> 2;
    const int wn   = wid & 3;
    const int r16  = lane & 15;
    const int kg   = lane >> 4;
    f32x4 acc[4][2] = {};
#pragma unroll
    for (int ks = 0; ks < 4; ++ks) {
        const int kb = ks * 32 + kg * 8;
        bf16x8 af[4], bg[2];
#pragma unroll
        for (int i = 0; i < 4; ++i) {
            const int r = wm * 64 + i * 16 + r16;
            const int byt = (r * 256 + kb * 2) ^ ((r & 7) << 4);
            af[i] = *(const bf16x8*)((const char*)aL + byt);
        }
#pragma unroll
        for (int j = 0; j < 2; ++j) {
            const int r = wn * 32 + j * 16 + r16;
            const int byt = (r * 256 + kb * 2) ^ ((r & 7) << 4);
            bg[j] = *(const bf16x8*)((const char*)bL + byt);
        }
#pragma unroll
        for (int i = 0; i < 4; ++i)
#pragma unroll
            for (int j = 0; j < 2; ++j)
                acc[i][j] = __builtin_amdgcn_mfma_f32_16x16x32_bf16(bg[j], af[i], acc[i][j], 0, 0, 0);
    }
    float* ob = Out + ((size_t)bz * NN + brow) * NN + bcol;
#pragma unroll
    for (int i = 0; i < 4; ++i) {
        const int r = wm * 64 + i * 16 + r16;
        const float u = xsL[r];
        float* orow = ob + (size_t)r * NN;
#pragma unroll
        for (int j = 0; j < 2; ++j) {
            const int cb = wn * 32 + j * 16 + kg * 4;
            const f32x4 v4 = *(const f32x4*)&ysL[cb];
            f32x4 o4;
#pragma unroll
            for (int q = 0; q < 4; ++q) {
                const float d  = acc[i][j][q];
                const float v  = v4[q];
                const float e1 = fmaf(-2.0f, d, 1.0f);
                const float den = fmaf(u, v, e1);
                float s = fmaf(-2.0f, d, u + v);
                s = fmaxf(s, 1e-12f);
                const float dn0 = s * __builtin_amdgcn_rsqf(s * den);
                const float dn = fminf(dn0, NMAX);
                o4[q] = __logf((1.0f + dn) * __builtin_amdgcn_rcpf(1.0f - dn));
            }
            *(f32x4*)(orow + cb) = o4;
        }
    }
}

extern "C" void kernel_launch(void* const* d_in, const int* in_sizes, int n_in,
                              void* d_out, int out_size, void* d_ws, size_t ws_size,
                              hipStream_t stream) {
    const float* X = (const float*)d_in[0];
    const float* Y = (const float*)d_in[1];
    float* O = (float*)d_out;
    const int b = in_sizes[0] / (NN * DK);   // = 4

    if (ws_size >= WS_REQ) {
        __bf16* Xb = (__bf16*)((char*)d_ws + WS_XB);
        __bf16* Yb = (__bf16*)((char*)d_ws + WS_YB);
        float2* XC = (float2*)((char*)d_ws + WS_XC);
        float2* YC = (float2*)((char*)d_ws + WS_YC);
        dim3 pg(b * NN / 16, 2, 1);
        prep_kernel<<<pg, dim3(256), 0, stream>>>(X, Y, Xb, Yb, XC, YC);
        dim3 grid(NN / BN, NN / BM, b);
        hyp_main<<<grid, dim3(512), 0, stream>>>(Xb, Yb, XC, YC, O);
    } else {
        dim3 grid(NN / BN, NN / BM, b);
        hyp_fallback<<<grid, dim3(512), 0, stream>>>(X, Y, O);
    }
}